// Round 2
// baseline (324.099 us; speedup 1.0000x reference)
//
#include <hip/hip_runtime.h>
#include <math.h>

#define NN 48
#define CC 512
#define KK 64
#define PP 1600
#define EPSF 1e-12f

typedef short short8 __attribute__((ext_vector_type(8)));
typedef float f32x4 __attribute__((ext_vector_type(4)));

static __device__ __forceinline__ unsigned short f2bf(float f) {
    unsigned u = __float_as_uint(f);
    u += 0x7fffu + ((u >> 16) & 1u);   // round-to-nearest-even
    return (unsigned short)(u >> 16);
}
static __device__ __forceinline__ unsigned pack2(float a, float b) {
    return (unsigned)f2bf(a) | ((unsigned)f2bf(b) << 16);
}

// Barrier WITHOUT the vmcnt(0) drain that __syncthreads() emits.
// LDS producer->consumer visibility needs only lgkmcnt(0); global loads
// prefetched into registers (and fire-and-forget global stores) legally
// stay in flight across the barrier. The compiler's waitcnt-insertion pass
// emits counted vmcnt(N) at first USE of prefetched values instead.
static __device__ __forceinline__ void barrier_nd() {
    asm volatile("s_waitcnt lgkmcnt(0)\n\ts_barrier" ::: "memory");
}

// ---------------------------------------------------------------------------
// Kernel 1: fused norm + attn + logits MFMA-GEMM + softmax.
// grid (25, N), block 256 (4 waves). Per block: 64 p (exact: 25*64 = 1600),
// all 512 c. Cross-chunk register prefetch: chunk cs+1's global loads issue
// at the top of iteration cs and are consumed one full iteration later.
// Hot-loop barriers are no-drain so those loads span both barriers.
// ---------------------------------------------------------------------------
__global__ __launch_bounds__(256, 4) void kn_logits(
    const float* __restrict__ x, const float* __restrict__ conv_w,
    const float* __restrict__ attn_w, const float* __restrict__ attn_b,
    unsigned short* __restrict__ wg, float* __restrict__ wsum,
    unsigned short* __restrict__ xbf)
{
    __shared__ unsigned short xt[64][76];   // [c_local][p] bf16, 152B rows
    __shared__ unsigned short cwb[64][72];  // [k][c_local] bf16, 144B rows
    __shared__ float attn_l[CC];
    __shared__ float red[16][64];
    __shared__ float invn_l[64];
    __shared__ float hmp_l[64];
    __shared__ float wsum_l[KK];

    const int n = blockIdx.y, p0 = blockIdx.x * 64, tid = threadIdx.x;
    const int q = tid & 15, cg = tid >> 4;        // x staging: p-quad, c-row-group
    const int wave = tid >> 6, lane = tid & 63;
    const int lq = lane >> 4, lm = lane & 15;     // MFMA lane decomposition
    const int kr = tid >> 2, cq = tid & 3;        // conv_w staging map

    for (int i = tid; i < CC; i += 256) attn_l[i] = attn_w[i];
    if (tid < KK) wsum_l[tid] = 0.f;

    f32x4 acc[4];
#pragma unroll
    for (int mt = 0; mt < 4; ++mt) acc[mt] = (f32x4){0.f, 0.f, 0.f, 0.f};
    float ss[4] = {0.f, 0.f, 0.f, 0.f};
    float ad[4] = {0.f, 0.f, 0.f, 0.f};

    const float* xb = x + (size_t)n * CC * PP;
    const float* wp0 = conv_w + (size_t)kr * CC + cq * 16;
    const float* xp0 = xb + (size_t)(cg * 4) * PP + p0 + 4 * q;

    // prologue: issue chunk-0 loads (in flight across the attn_l barrier)
    float4 wv[4], xv[4];
#pragma unroll
    for (int j = 0; j < 4; ++j) wv[j] = *(const float4*)(wp0 + 4 * j);
#pragma unroll
    for (int j = 0; j < 4; ++j) xv[j] = *(const float4*)(xp0 + (size_t)j * PP);

    __syncthreads();   // attn_l / wsum_l ready (cold path, full drain ok)

#pragma unroll 1
    for (int cs = 0; cs < 8; ++cs) {
        // issue chunk cs+1 loads FIRST (no dependencies -> stay in flight
        // across both barriers; counted vmcnt at use next iteration)
        float4 wn[4], xn_[4];
        if (cs < 7) {
            const float* wp = wp0 + (cs + 1) * 64;
            const float* xp = xp0 + (size_t)(cs + 1) * 64 * PP;
#pragma unroll
            for (int j = 0; j < 4; ++j) wn[j] = *(const float4*)(wp + 4 * j);
#pragma unroll
            for (int j = 0; j < 4; ++j) xn_[j] = *(const float4*)(xp + (size_t)j * PP);
        }
        // process conv_w tile (loaded last iteration) -> bf16 LDS
#pragma unroll
        for (int j = 0; j < 4; ++j) {
            uint2 u = {pack2(wv[j].x, wv[j].y), pack2(wv[j].z, wv[j].w)};
            *(uint2*)&cwb[kr][cq * 16 + 4 * j] = u;
        }
        // process x tile: stats + bf16 LDS + bf16 global writeback
        const int cbase = cs * 64 + cg * 4;
#pragma unroll
        for (int j = 0; j < 4; ++j) {
            float4 v = xv[j];
            const float aw = attn_l[cbase + j];
            ss[0] += v.x * v.x; ss[1] += v.y * v.y;
            ss[2] += v.z * v.z; ss[3] += v.w * v.w;
            ad[0] += fmaxf(v.x, 0.f) * aw; ad[1] += fmaxf(v.y, 0.f) * aw;
            ad[2] += fmaxf(v.z, 0.f) * aw; ad[3] += fmaxf(v.w, 0.f) * aw;
            uint2 u = {pack2(v.x, v.y), pack2(v.z, v.w)};
            *(uint2*)&xt[cg * 4 + j][4 * q] = u;
            if (xbf)
                *(uint2*)(xbf + ((size_t)n * CC + cbase + j) * PP + p0 + 4 * q) = u;
        }
        barrier_nd();
#pragma unroll
        for (int ks = 0; ks < 2; ++ks) {
            short8 af[4];
#pragma unroll
            for (int mt = 0; mt < 4; ++mt)
                af[mt] = *(const short8*)&cwb[mt * 16 + lm][ks * 32 + lq * 8];
            const int pl = wave * 16 + lm;
            const int cb = ks * 32 + lq * 8;
            short8 bv;
#pragma unroll
            for (int j = 0; j < 8; ++j) bv[j] = (short)xt[cb + j][pl];
#pragma unroll
            for (int mt = 0; mt < 4; ++mt)
                acc[mt] = __builtin_amdgcn_mfma_f32_16x16x32_bf16(
                    af[mt], bv, acc[mt], 0, 0, 0);
        }
        barrier_nd();
        if (cs < 7) {
#pragma unroll
            for (int j = 0; j < 4; ++j) { wv[j] = wn[j]; xv[j] = xn_[j]; }
        }
    }

    // block reductions: invnorm and hmp per p (fp32)
#pragma unroll
    for (int j = 0; j < 4; ++j) red[cg][4 * q + j] = ss[j];
    __syncthreads();
    if (tid < 64) {
        float S = 0.f;
#pragma unroll
        for (int l = 0; l < 16; ++l) S += red[l][tid];
        invn_l[tid] = 1.f / fmaxf(sqrtf(S), EPSF);
    }
    __syncthreads();
#pragma unroll
    for (int j = 0; j < 4; ++j) red[cg][4 * q + j] = ad[j];
    __syncthreads();
    if (tid < 64) {
        float A = 0.f;
#pragma unroll
        for (int l = 0; l < 16; ++l) A += red[l][tid];
        hmp_l[tid] = fmaxf(A + attn_b[0], 0.f);
    }
    __syncthreads();

    // softmax over k=64 per p, entirely in registers (C-layout + shfl_xor)
    const int pl = wave * 16 + lm;
    const float inv = invn_l[pl];
    const float hp = hmp_l[pl];
    float mx = -1e30f;
#pragma unroll
    for (int mt = 0; mt < 4; ++mt)
#pragma unroll
        for (int r = 0; r < 4; ++r) {
            const float l = acc[mt][r] * inv;
            acc[mt][r] = l;
            mx = fmaxf(mx, l);
        }
    mx = fmaxf(mx, __shfl_xor(mx, 16));
    mx = fmaxf(mx, __shfl_xor(mx, 32));
    float s = 0.f;
#pragma unroll
    for (int mt = 0; mt < 4; ++mt)
#pragma unroll
        for (int r = 0; r < 4; ++r) {
            const float e = __expf(acc[mt][r] - mx);
            acc[mt][r] = e;
            s += e;
        }
    s += __shfl_xor(s, 16);
    s += __shfl_xor(s, 32);
    const float sden = hp / s;

    unsigned short* wrb = wg + (size_t)n * KK * PP + p0;
#pragma unroll
    for (int mt = 0; mt < 4; ++mt)
#pragma unroll
        for (int r = 0; r < 4; ++r) {
            const int k = mt * 16 + lq * 4 + r;
            const float w0 = acc[mt][r] * sden;
            float wk = w0;
#pragma unroll
            for (int o = 1; o < 16; o <<= 1) wk += __shfl_xor(wk, o);
            if (lm == 0) atomicAdd(&wsum_l[k], wk);
            wrb[(size_t)k * PP + pl] = f2bf(w0 * inv);
        }
    __syncthreads();
    if (tid < KK) atomicAdd(&wsum[n * KK + tid], wsum_l[tid]);
}

// ---------------------------------------------------------------------------
// Kernel 2: term1[k,c] = sum_p w'[k,p] * x[c,p] via MFMA (contraction over p;
// both operands p-contiguous -> b128 fragments). grid (8 c-chunks, N, 4 p-
// chunks) = 1536 blocks (6/CU). 1-deep register prefetch issued BEFORE the
// LDS stores; no-drain barriers keep it in flight across the whole iteration.
// XB: x from bf16 sidecar; else convert fp32 x inline.
// ---------------------------------------------------------------------------
template <bool XB>
__global__ __launch_bounds__(256) void kn_term1(
    const float* __restrict__ xf, const unsigned short* __restrict__ xbf,
    const unsigned short* __restrict__ wgq, float* __restrict__ term1p)
{
    __shared__ unsigned short wt[64][40];    // [k][32p] bf16, rows 80B
    __shared__ unsigned short xt2[64][40];   // [c_local][32p] bf16
    const int c0 = blockIdx.x * 64, n = blockIdx.y, ph = blockIdx.z;
    const int tid = threadIdx.x;
    const int wave = tid >> 6, lane = tid & 63, lq = lane >> 4, lm = lane & 15;
    const int koff = (wave >> 1) * 32, coff = (wave & 1) * 32;
    const int s_begin = (50 * ph) >> 2, s_end = (50 * (ph + 1)) >> 2;
    const int rA = tid >> 2, cq = tid & 3;   // staging map (same for A and B)

    f32x4 acc[2][2];
#pragma unroll
    for (int mt = 0; mt < 2; ++mt)
#pragma unroll
        for (int nt = 0; nt < 2; ++nt) acc[mt][nt] = (f32x4){0.f, 0.f, 0.f, 0.f};

    const unsigned short* wb = wgq + (size_t)n * KK * PP + (size_t)rA * PP + cq * 8;
    const unsigned short* xbb = xbf + ((size_t)n * CC + c0 + rA) * PP + cq * 8;
    const float* xfb = xf + ((size_t)n * CC + c0 + rA) * PP + cq * 8;

    auto ldB = [&](int p) -> uint4 {
        if (XB) {
            return *(const uint4*)(xbb + p);
        } else {
            const float* sp = xfb + p;
            float4 a = *(const float4*)sp, b = *(const float4*)(sp + 4);
            return make_uint4(pack2(a.x, a.y), pack2(a.z, a.w),
                              pack2(b.x, b.y), pack2(b.z, b.w));
        }
    };

    uint4 pa = *(const uint4*)(wb + s_begin * 32);
    uint4 pb = ldB(s_begin * 32);

    for (int ps = s_begin; ps < s_end; ++ps) {
        // prefetch FIRST (no deps); the LDS stores below wait counted-vmcnt
        // on pa/pb only, leaving na/nb in flight across both barriers
        uint4 na, nb;
        if (ps + 1 < s_end) {
            na = *(const uint4*)(wb + (ps + 1) * 32);
            nb = ldB((ps + 1) * 32);
        }
        *(uint4*)&wt[rA][cq * 8] = pa;
        *(uint4*)&xt2[rA][cq * 8] = pb;
        barrier_nd();
        short8 af[2], bv[2];
#pragma unroll
        for (int mt = 0; mt < 2; ++mt)
            af[mt] = *(const short8*)&wt[koff + mt * 16 + lm][lq * 8];
#pragma unroll
        for (int nt = 0; nt < 2; ++nt)
            bv[nt] = *(const short8*)&xt2[coff + nt * 16 + lm][lq * 8];
#pragma unroll
        for (int mt = 0; mt < 2; ++mt)
#pragma unroll
            for (int nt = 0; nt < 2; ++nt)
                acc[mt][nt] = __builtin_amdgcn_mfma_f32_16x16x32_bf16(
                    af[mt], bv[nt], acc[mt][nt], 0, 0, 0);
        barrier_nd();
        pa = na; pb = nb;
    }

    float* ob = term1p + ((size_t)ph * NN + n) * KK * CC + c0 + coff;
#pragma unroll
    for (int mt = 0; mt < 2; ++mt)
#pragma unroll
        for (int r = 0; r < 4; ++r) {
            const int k = koff + mt * 16 + lq * 4 + r;
#pragma unroll
            for (int nt = 0; nt < 2; ++nt)
                ob[(size_t)k * CC + nt * 16 + lm] = acc[mt][nt][r];
        }
}

// ---------------------------------------------------------------------------
// Kernel 3: vlad = sum(term1 partials) - wsum*centroids; intra L2-normalize;
// per-n global sumsq. grid (K, N), block 128.
// ---------------------------------------------------------------------------
__global__ __launch_bounds__(128) void kn_vlad(
    const float* __restrict__ term1p, const float* __restrict__ wsum,
    const float* __restrict__ cent, float* __restrict__ out,
    float* __restrict__ nsum)
{
    const int k = blockIdx.x, n = blockIdx.y, tid = threadIdx.x;
    const size_t base = ((size_t)n * KK + k) * CC;
    const size_t NKC = (size_t)NN * KK * CC;
    const float ws = wsum[n * KK + k];
    const int c = tid * 4;

    float4 ce = *(const float4*)(cent + (size_t)k * CC + c);
    float4 v = {-ws * ce.x, -ws * ce.y, -ws * ce.z, -ws * ce.w};
#pragma unroll
    for (int h = 0; h < 4; ++h) {
        float4 a = *(const float4*)(term1p + h * NKC + base + c);
        v.x += a.x; v.y += a.y; v.z += a.z; v.w += a.w;
    }

    float s = v.x * v.x + v.y * v.y + v.z * v.z + v.w * v.w;
#pragma unroll
    for (int o = 32; o >= 1; o >>= 1) s += __shfl_down(s, o, 64);

    __shared__ float rb[2];
    __shared__ float sinv;
    if ((tid & 63) == 0) rb[tid >> 6] = s;
    __syncthreads();
    if (tid == 0) {
        const float S = rb[0] + rb[1];
        const float inv = 1.f / fmaxf(sqrtf(S), EPSF);
        sinv = inv;
        atomicAdd(&nsum[n], S * inv * inv);
    }
    __syncthreads();
    const float inv = sinv;
    float4 o4 = {v.x * inv, v.y * inv, v.z * inv, v.w * inv};
    *(float4*)(out + base + c) = o4;
}

// ---------------------------------------------------------------------------
// Kernel 4: global L2 normalize per n.
// ---------------------------------------------------------------------------
__global__ __launch_bounds__(256) void kn_scale(
    float* __restrict__ out, const float* __restrict__ nsum)
{
    const int n = blockIdx.y;
    const size_t off = ((size_t)blockIdx.x * 256 + threadIdx.x) * 4;
    const float g = 1.f / fmaxf(sqrtf(nsum[n]), EPSF);
    float4 v = *(float4*)(out + (size_t)n * KK * CC + off);
    v.x *= g; v.y *= g; v.z *= g; v.w *= g;
    *(float4*)(out + (size_t)n * KK * CC + off) = v;
}

extern "C" void kernel_launch(void* const* d_in, const int* in_sizes, int n_in,
                              void* d_out, int out_size, void* d_ws, size_t ws_size,
                              hipStream_t stream)
{
    (void)in_sizes; (void)n_in; (void)out_size;
    const float* x      = (const float*)d_in[0];
    const float* conv_w = (const float*)d_in[1];
    const float* attn_w = (const float*)d_in[2];
    const float* attn_b = (const float*)d_in[3];
    const float* cent   = (const float*)d_in[4];
    float* out = (float*)d_out;

    // ws layout: term1p[4][N][K][C] f32 | wsum f32 | nsum f32(pad) | wg bf16 | xbf bf16
    char* w = (char*)d_ws;
    float* term1p = (float*)w;            w += (size_t)4 * NN * KK * CC * 4;
    float* wsum   = (float*)w;            w += (size_t)NN * KK * 4;
    float* nsum   = (float*)w;            w += 256;
    unsigned short* wg  = (unsigned short*)w; w += (size_t)NN * KK * PP * 2;
    unsigned short* xbf = (unsigned short*)w;
    const size_t need_xb = (size_t)(w - (char*)d_ws) + (size_t)NN * CC * PP * 2;
    const bool xb = ws_size >= need_xb;

    hipMemsetAsync(wsum, 0, NN * KK * sizeof(float), stream);
    hipMemsetAsync(nsum, 0, NN * sizeof(float), stream);

    kn_logits<<<dim3(25, NN), 256, 0, stream>>>(x, conv_w, attn_w, attn_b,
                                                wg, wsum, xb ? xbf : nullptr);
    if (xb)
        kn_term1<true><<<dim3(8, NN, 4), 256, 0, stream>>>(x, xbf, wg, term1p);
    else
        kn_term1<false><<<dim3(8, NN, 4), 256, 0, stream>>>(x, xbf, wg, term1p);
    kn_vlad <<<dim3(KK, NN), 128, 0, stream>>>(term1p, wsum, cent, out, nsum);
    kn_scale<<<dim3(32, NN), 256, 0, stream>>>(out, nsum);
}

// Round 3
// 318.589 us; speedup vs baseline: 1.0173x; 1.0173x over previous
//
#include <hip/hip_runtime.h>
#include <math.h>

#define NN 48
#define CC 512
#define KK 64
#define PP 1600
#define EPSF 1e-12f

typedef short short8 __attribute__((ext_vector_type(8)));
typedef float f32x4 __attribute__((ext_vector_type(4)));

static __device__ __forceinline__ unsigned short f2bf(float f) {
    unsigned u = __float_as_uint(f);
    u += 0x7fffu + ((u >> 16) & 1u);   // round-to-nearest-even
    return (unsigned short)(u >> 16);
}
static __device__ __forceinline__ unsigned pack2(float a, float b) {
    return (unsigned)f2bf(a) | ((unsigned)f2bf(b) << 16);
}

// LDS-only barrier: lgkmcnt(0) + s_barrier. Global (vm) ops stay in flight.
static __device__ __forceinline__ void barrier_nd() {
    asm volatile("s_waitcnt lgkmcnt(0)\n\ts_barrier" ::: "memory");
}

typedef __attribute__((address_space(3))) unsigned int as3_uint;
typedef __attribute__((address_space(1))) const unsigned int as1_cuint;
// 16-byte global->LDS DMA (per-lane global src; LDS dest = wave base + lane*16)
static __device__ __forceinline__ void dma16(const void* g, void* l) {
    __builtin_amdgcn_global_load_lds((as1_cuint*)g, (as3_uint*)l, 16, 0, 0);
}

// ---------------------------------------------------------------------------
// Kernel 1: fused norm + attn + logits MFMA-GEMM + softmax.
// grid (25, N), block 256 (4 waves), 64 p per block (exact), c swept in 8
// chunks of 64. x chunk is DMA'd (global_load_lds, dwordx4) into a double-
// buffered fp32 LDS tile with an XOR-swizzled SOURCE so the linear DMA
// layout reads conflict-free. Counted s_waitcnt vmcnt(4) (sched_barrier-
// fenced) keeps the next tile in flight across the whole iteration; no
// vmcnt(0) drain in the loop. Stats and MFMA B-fragments both read the
// fp32 tile (bf16 conversion inline, same rounding as xbf writeback).
// ---------------------------------------------------------------------------
__global__ __launch_bounds__(256, 3) void kn_logits(
    const float* __restrict__ x, const float* __restrict__ conv_w,
    const float* __restrict__ attn_w, const float* __restrict__ attn_b,
    unsigned short* __restrict__ wg, float* __restrict__ wsum,
    unsigned short* __restrict__ xbf)
{
    __shared__ float xf[2][64][64];          // 32 KB, DMA-staged, src-swizzled
    __shared__ unsigned short cwb[64][72];   // [k][c_local] bf16, 144B rows
    __shared__ float attn_l[CC];

    const int n = blockIdx.y, p0 = blockIdx.x * 64, tid = threadIdx.x;
    const int q = tid & 15, cg = tid >> 4;        // stats map: p-quad, c-row-group
    const int wave = tid >> 6, lane = tid & 63;
    const int lq = lane >> 4, lm = lane & 15;     // MFMA lane decomposition
    const int kr = tid >> 2, cq = tid & 3;        // conv_w staging map

    const float* xb = x + (size_t)n * CC * PP;
    const int dsub = lane >> 4, dslot = lane & 15;   // DMA lane geometry

    // DMA one 64c x 64p fp32 chunk into xf[nb]. Physical slot s of row r
    // holds logical p-group (s ^ (r&7)) -> readers apply the same XOR.
    auto dma_chunk = [&](int cs, int nb) {
#pragma unroll
        for (int i = 0; i < 4; ++i) {
            const int row = (i * 4 + wave) * 4 + dsub;
            const int qlog = dslot ^ (row & 7);
            const float* g = xb + (size_t)(cs * 64 + row) * PP + p0 + qlog * 4;
            dma16((const void*)g, (void*)&xf[nb][row][dslot * 4]);
        }
    };

    dma_chunk(0, 0);   // chunk 0 in flight immediately

    for (int i = tid; i < CC; i += 256) attn_l[i] = attn_w[i];

    float4 wv[4];
    const float* wp0 = conv_w + (size_t)kr * CC + cq * 16;
#pragma unroll
    for (int j = 0; j < 4; ++j) wv[j] = *(const float4*)(wp0 + 4 * j);

    f32x4 acc[4];
#pragma unroll
    for (int mt = 0; mt < 4; ++mt) acc[mt] = (f32x4){0.f, 0.f, 0.f, 0.f};
    float ss[4] = {0.f, 0.f, 0.f, 0.f};
    float ad[4] = {0.f, 0.f, 0.f, 0.f};

#pragma unroll 1
    for (int cs = 0; cs < 8; ++cs) {
        const int b = cs & 1;
        barrier_nd();                       // prev iter's xf[b^1]/cwb reads done
        const int csn = cs < 7 ? cs + 1 : 7;    // clamp keeps vmcnt geometry
        dma_chunk(csn, b ^ 1);
        // pack conv_w chunk cs -> cwb (LDS writes, covered by next barrier)
#pragma unroll
        for (int j = 0; j < 4; ++j) {
            uint2 u = {pack2(wv[j].x, wv[j].y), pack2(wv[j].z, wv[j].w)};
            *(uint2*)&cwb[kr][cq * 16 + 4 * j] = u;
        }
        // prefetch next conv_w chunk (compiler-managed, L2-hot)
        float4 wn[4];
        if (cs < 7) {
            const float* wp = wp0 + (cs + 1) * 64;
#pragma unroll
            for (int j = 0; j < 4; ++j) wn[j] = *(const float4*)(wp + 4 * j);
        }
        __builtin_amdgcn_sched_barrier(0);
        asm volatile("s_waitcnt vmcnt(4)" ::: "memory");  // tile cs landed
        __builtin_amdgcn_sched_barrier(0);
        barrier_nd();                       // all waves landed + cwb visible

        // stats + xbf writeback from xf[b]
        const int cbase = cs * 64 + cg * 4;
#pragma unroll
        for (int j = 0; j < 4; ++j) {
            const int row = cg * 4 + j;
            const float4 v = *(const float4*)&xf[b][row][(q ^ (row & 7)) * 4];
            const float aw = attn_l[cbase + j];
            ss[0] += v.x * v.x; ss[1] += v.y * v.y;
            ss[2] += v.z * v.z; ss[3] += v.w * v.w;
            ad[0] += fmaxf(v.x, 0.f) * aw; ad[1] += fmaxf(v.y, 0.f) * aw;
            ad[2] += fmaxf(v.z, 0.f) * aw; ad[3] += fmaxf(v.w, 0.f) * aw;
            uint2 u = {pack2(v.x, v.y), pack2(v.z, v.w)};
            if (xbf)
                *(uint2*)(xbf + ((size_t)n * CC + cbase + j) * PP + p0 + 4 * q) = u;
        }
        // MFMA: A from cwb (bf16), B from xf[b] fp32 + inline convert
        const int pl = wave * 16 + lm;
#pragma unroll
        for (int ks = 0; ks < 2; ++ks) {
            short8 af[4];
#pragma unroll
            for (int mt = 0; mt < 4; ++mt)
                af[mt] = *(const short8*)&cwb[mt * 16 + lm][ks * 32 + lq * 8];
            const int cb = ks * 32 + lq * 8;
            short8 bv;
#pragma unroll
            for (int jj = 0; jj < 8; ++jj) {
                const int row = cb + jj;
                const float xv = xf[b][row][(((pl >> 2) ^ (row & 7)) << 2) + (pl & 3)];
                bv[jj] = (short)f2bf(xv);
            }
#pragma unroll
            for (int mt = 0; mt < 4; ++mt)
                acc[mt] = __builtin_amdgcn_mfma_f32_16x16x32_bf16(
                    af[mt], bv, acc[mt], 0, 0, 0);
        }
        if (cs < 7) {
#pragma unroll
            for (int j = 0; j < 4; ++j) wv[j] = wn[j];
        }
    }

    __syncthreads();   // full drain: clamped DMA quiesced, xf reusable

    // epilogue reductions aliased into the (dead) xf buffers
    float* red    = &xf[0][0][0];    // [16][64]
    float* invn_l = &xf[1][0][0];    // 64
    float* hmp_l  = invn_l + 64;
    float* wsum_l = invn_l + 128;

    if (tid < KK) wsum_l[tid] = 0.f;
#pragma unroll
    for (int j = 0; j < 4; ++j) red[cg * 64 + 4 * q + j] = ss[j];
    __syncthreads();
    if (tid < 64) {
        float S = 0.f;
#pragma unroll
        for (int l = 0; l < 16; ++l) S += red[l * 64 + tid];
        invn_l[tid] = 1.f / fmaxf(sqrtf(S), EPSF);
    }
    __syncthreads();
#pragma unroll
    for (int j = 0; j < 4; ++j) red[cg * 64 + 4 * q + j] = ad[j];
    __syncthreads();
    if (tid < 64) {
        float A = 0.f;
#pragma unroll
        for (int l = 0; l < 16; ++l) A += red[l * 64 + tid];
        hmp_l[tid] = fmaxf(A + attn_b[0], 0.f);
    }
    __syncthreads();

    // softmax over k=64 per p, entirely in registers
    const int pl = wave * 16 + lm;
    const float inv = invn_l[pl];
    const float hp = hmp_l[pl];
    float mx = -1e30f;
#pragma unroll
    for (int mt = 0; mt < 4; ++mt)
#pragma unroll
        for (int r = 0; r < 4; ++r) {
            const float l = acc[mt][r] * inv;
            acc[mt][r] = l;
            mx = fmaxf(mx, l);
        }
    mx = fmaxf(mx, __shfl_xor(mx, 16));
    mx = fmaxf(mx, __shfl_xor(mx, 32));
    float s = 0.f;
#pragma unroll
    for (int mt = 0; mt < 4; ++mt)
#pragma unroll
        for (int r = 0; r < 4; ++r) {
            const float e = __expf(acc[mt][r] - mx);
            acc[mt][r] = e;
            s += e;
        }
    s += __shfl_xor(s, 16);
    s += __shfl_xor(s, 32);
    const float sden = hp / s;

    unsigned short* wrb = wg + (size_t)n * KK * PP + p0;
#pragma unroll
    for (int mt = 0; mt < 4; ++mt)
#pragma unroll
        for (int r = 0; r < 4; ++r) {
            const int k = mt * 16 + lq * 4 + r;
            const float w0 = acc[mt][r] * sden;
            float wk = w0;
#pragma unroll
            for (int o = 1; o < 16; o <<= 1) wk += __shfl_xor(wk, o);
            if (lm == 0) atomicAdd(&wsum_l[k], wk);
            wrb[(size_t)k * PP + pl] = f2bf(w0 * inv);
        }
    __syncthreads();
    if (tid < KK) atomicAdd(&wsum[n * KK + tid], wsum_l[tid]);
}

// ---------------------------------------------------------------------------
// Kernel 2 (bf16 sidecar path): term1[k,c] = sum_p w'[k,p] * x[c,p] via MFMA.
// grid (8 c-chunks, N, 4 p-chunks) = 1536 blocks (6/CU, all resident).
// Both tiles DMA'd (global_load_lds) into double-buffered LDS with source-
// XOR swizzle; exact counted vmcnt(2) per iteration, no in-loop drain.
// ---------------------------------------------------------------------------
__global__ __launch_bounds__(256) void kn_term1_dma(
    const unsigned short* __restrict__ xbf,
    const unsigned short* __restrict__ wgq, float* __restrict__ term1p)
{
    __shared__ unsigned short wt[2][64][32];    // [k][32p] bf16, linear 64B rows
    __shared__ unsigned short xt2[2][64][32];   // [c_local][32p]
    const int c0 = blockIdx.x * 64, n = blockIdx.y, ph = blockIdx.z;
    const int tid = threadIdx.x;
    const int wave = tid >> 6, lane = tid & 63, lq = lane >> 4, lm = lane & 15;
    const int koff = (wave >> 1) * 32, coff = (wave & 1) * 32;
    const int s_begin = (50 * ph) >> 2, s_end = (50 * (ph + 1)) >> 2;

    const int drow = wave * 16 + (lane >> 2);   // DMA row (k or c_local)
    const int dslot = lane & 3;                 // 16B slot within 64B row
    const int dq = dslot ^ (drow & 3);          // logical 8-elem group (src swizzle)

    const unsigned short* wsrc = wgq + (size_t)n * KK * PP + (size_t)drow * PP + dq * 8;
    const unsigned short* xsrc = xbf + ((size_t)n * CC + c0 + drow) * PP + dq * 8;

    auto dma_tiles = [&](int ps, int nb) {
        dma16((const void*)(wsrc + ps * 32), (void*)&wt[nb][drow][dslot * 8]);
        dma16((const void*)(xsrc + ps * 32), (void*)&xt2[nb][drow][dslot * 8]);
    };

    f32x4 acc[2][2];
#pragma unroll
    for (int mt = 0; mt < 2; ++mt)
#pragma unroll
        for (int nt = 0; nt < 2; ++nt) acc[mt][nt] = (f32x4){0.f, 0.f, 0.f, 0.f};

    dma_tiles(s_begin, 0);

#pragma unroll 1
    for (int ps = s_begin; ps < s_end; ++ps) {
        const int b = (ps - s_begin) & 1;
        barrier_nd();                          // prev iter's tile reads done
        const int psn = (ps + 1 < s_end) ? ps + 1 : ps;   // clamp
        dma_tiles(psn, b ^ 1);
        __builtin_amdgcn_sched_barrier(0);
        asm volatile("s_waitcnt vmcnt(2)" ::: "memory");  // tile ps landed
        __builtin_amdgcn_sched_barrier(0);
        barrier_nd();                          // all waves landed

        short8 af[2], bv[2];
#pragma unroll
        for (int mt = 0; mt < 2; ++mt) {
            const int row = koff + mt * 16 + lm;
            af[mt] = *(const short8*)&wt[b][row][(lq ^ (row & 3)) * 8];
        }
#pragma unroll
        for (int nt = 0; nt < 2; ++nt) {
            const int row = coff + nt * 16 + lm;
            bv[nt] = *(const short8*)&xt2[b][row][(lq ^ (row & 3)) * 8];
        }
#pragma unroll
        for (int mt = 0; mt < 2; ++mt)
#pragma unroll
            for (int nt = 0; nt < 2; ++nt)
                acc[mt][nt] = __builtin_amdgcn_mfma_f32_16x16x32_bf16(
                    af[mt], bv[nt], acc[mt][nt], 0, 0, 0);
    }
    asm volatile("s_waitcnt vmcnt(0)" ::: "memory");   // quiesce clamped DMA

    float* ob = term1p + ((size_t)ph * NN + n) * KK * CC + c0 + coff;
#pragma unroll
    for (int mt = 0; mt < 2; ++mt)
#pragma unroll
        for (int r = 0; r < 4; ++r) {
            const int k = koff + mt * 16 + lq * 4 + r;
#pragma unroll
            for (int nt = 0; nt < 2; ++nt)
                ob[(size_t)k * CC + nt * 16 + lm] = acc[mt][nt][r];
        }
}

// ---------------------------------------------------------------------------
// Kernel 2 fallback (no bf16 sidecar): old register-staged version, fp32 x.
// ---------------------------------------------------------------------------
__global__ __launch_bounds__(256) void kn_term1_f32(
    const float* __restrict__ xf, const unsigned short* __restrict__ wgq,
    float* __restrict__ term1p)
{
    __shared__ unsigned short wt[64][40];
    __shared__ unsigned short xt2[64][40];
    const int c0 = blockIdx.x * 64, n = blockIdx.y, ph = blockIdx.z;
    const int tid = threadIdx.x;
    const int wave = tid >> 6, lane = tid & 63, lq = lane >> 4, lm = lane & 15;
    const int koff = (wave >> 1) * 32, coff = (wave & 1) * 32;
    const int s_begin = (50 * ph) >> 2, s_end = (50 * (ph + 1)) >> 2;
    const int rA = tid >> 2, cq = tid & 3;

    f32x4 acc[2][2];
#pragma unroll
    for (int mt = 0; mt < 2; ++mt)
#pragma unroll
        for (int nt = 0; nt < 2; ++nt) acc[mt][nt] = (f32x4){0.f, 0.f, 0.f, 0.f};

    const unsigned short* wb = wgq + (size_t)n * KK * PP + (size_t)rA * PP + cq * 8;
    const float* xfb = xf + ((size_t)n * CC + c0 + rA) * PP + cq * 8;

    auto ldB = [&](int p) -> uint4 {
        const float* sp = xfb + p;
        float4 a = *(const float4*)sp, b = *(const float4*)(sp + 4);
        return make_uint4(pack2(a.x, a.y), pack2(a.z, a.w),
                          pack2(b.x, b.y), pack2(b.z, b.w));
    };

    uint4 pa = *(const uint4*)(wb + s_begin * 32);
    uint4 pb = ldB(s_begin * 32);

    for (int ps = s_begin; ps < s_end; ++ps) {
        uint4 na, nb;
        if (ps + 1 < s_end) {
            na = *(const uint4*)(wb + (ps + 1) * 32);
            nb = ldB((ps + 1) * 32);
        }
        *(uint4*)&wt[rA][cq * 8] = pa;
        *(uint4*)&xt2[rA][cq * 8] = pb;
        __syncthreads();
        short8 af[2], bv[2];
#pragma unroll
        for (int mt = 0; mt < 2; ++mt)
            af[mt] = *(const short8*)&wt[koff + mt * 16 + lm][lq * 8];
#pragma unroll
        for (int nt = 0; nt < 2; ++nt)
            bv[nt] = *(const short8*)&xt2[coff + nt * 16 + lm][lq * 8];
#pragma unroll
        for (int mt = 0; mt < 2; ++mt)
#pragma unroll
            for (int nt = 0; nt < 2; ++nt)
                acc[mt][nt] = __builtin_amdgcn_mfma_f32_16x16x32_bf16(
                    af[mt], bv[nt], acc[mt][nt], 0, 0, 0);
        __syncthreads();
        pa = na; pb = nb;
    }

    float* ob = term1p + ((size_t)ph * NN + n) * KK * CC + c0 + coff;
#pragma unroll
    for (int mt = 0; mt < 2; ++mt)
#pragma unroll
        for (int r = 0; r < 4; ++r) {
            const int k = koff + mt * 16 + lq * 4 + r;
#pragma unroll
            for (int nt = 0; nt < 2; ++nt)
                ob[(size_t)k * CC + nt * 16 + lm] = acc[mt][nt][r];
        }
}

// ---------------------------------------------------------------------------
// Kernel 3: vlad = sum(term1 partials) - wsum*centroids; intra L2-normalize;
// per-n global sumsq. grid (K, N), block 128.
// ---------------------------------------------------------------------------
__global__ __launch_bounds__(128) void kn_vlad(
    const float* __restrict__ term1p, const float* __restrict__ wsum,
    const float* __restrict__ cent, float* __restrict__ out,
    float* __restrict__ nsum)
{
    const int k = blockIdx.x, n = blockIdx.y, tid = threadIdx.x;
    const size_t base = ((size_t)n * KK + k) * CC;
    const size_t NKC = (size_t)NN * KK * CC;
    const float ws = wsum[n * KK + k];
    const int c = tid * 4;

    float4 ce = *(const float4*)(cent + (size_t)k * CC + c);
    float4 v = {-ws * ce.x, -ws * ce.y, -ws * ce.z, -ws * ce.w};
#pragma unroll
    for (int h = 0; h < 4; ++h) {
        float4 a = *(const float4*)(term1p + h * NKC + base + c);
        v.x += a.x; v.y += a.y; v.z += a.z; v.w += a.w;
    }

    float s = v.x * v.x + v.y * v.y + v.z * v.z + v.w * v.w;
#pragma unroll
    for (int o = 32; o >= 1; o >>= 1) s += __shfl_down(s, o, 64);

    __shared__ float rb[2];
    __shared__ float sinv;
    if ((tid & 63) == 0) rb[tid >> 6] = s;
    __syncthreads();
    if (tid == 0) {
        const float S = rb[0] + rb[1];
        const float inv = 1.f / fmaxf(sqrtf(S), EPSF);
        sinv = inv;
        atomicAdd(&nsum[n], S * inv * inv);
    }
    __syncthreads();
    const float inv = sinv;
    float4 o4 = {v.x * inv, v.y * inv, v.z * inv, v.w * inv};
    *(float4*)(out + base + c) = o4;
}

// ---------------------------------------------------------------------------
// Kernel 4: global L2 normalize per n.
// ---------------------------------------------------------------------------
__global__ __launch_bounds__(256) void kn_scale(
    float* __restrict__ out, const float* __restrict__ nsum)
{
    const int n = blockIdx.y;
    const size_t off = ((size_t)blockIdx.x * 256 + threadIdx.x) * 4;
    const float g = 1.f / fmaxf(sqrtf(nsum[n]), EPSF);
    float4 v = *(float4*)(out + (size_t)n * KK * CC + off);
    v.x *= g; v.y *= g; v.z *= g; v.w *= g;
    *(float4*)(out + (size_t)n * KK * CC + off) = v;
}

extern "C" void kernel_launch(void* const* d_in, const int* in_sizes, int n_in,
                              void* d_out, int out_size, void* d_ws, size_t ws_size,
                              hipStream_t stream)
{
    (void)in_sizes; (void)n_in; (void)out_size;
    const float* x      = (const float*)d_in[0];
    const float* conv_w = (const float*)d_in[1];
    const float* attn_w = (const float*)d_in[2];
    const float* attn_b = (const float*)d_in[3];
    const float* cent   = (const float*)d_in[4];
    float* out = (float*)d_out;

    // ws layout: term1p[4][N][K][C] f32 | wsum f32 | nsum f32(pad) | wg bf16 | xbf bf16
    char* w = (char*)d_ws;
    float* term1p = (float*)w;            w += (size_t)4 * NN * KK * CC * 4;
    float* wsum   = (float*)w;            w += (size_t)NN * KK * 4;
    float* nsum   = (float*)w;            w += 256;
    unsigned short* wg  = (unsigned short*)w; w += (size_t)NN * KK * PP * 2;
    unsigned short* xbf = (unsigned short*)w;
    const size_t need_xb = (size_t)(w - (char*)d_ws) + (size_t)NN * CC * PP * 2;
    const bool xb = ws_size >= need_xb;

    hipMemsetAsync(wsum, 0, NN * KK * sizeof(float), stream);
    hipMemsetAsync(nsum, 0, NN * sizeof(float), stream);

    kn_logits<<<dim3(25, NN), 256, 0, stream>>>(x, conv_w, attn_w, attn_b,
                                                wg, wsum, xb ? xbf : nullptr);
    if (xb)
        kn_term1_dma<<<dim3(8, NN, 4), 256, 0, stream>>>(xbf, wg, term1p);
    else
        kn_term1_f32<<<dim3(8, NN, 4), 256, 0, stream>>>(x, wg, term1p);
    kn_vlad <<<dim3(KK, NN), 128, 0, stream>>>(term1p, wsum, cent, out, nsum);
    kn_scale<<<dim3(32, NN), 256, 0, stream>>>(out, nsum);
}

// Round 4
// 300.835 us; speedup vs baseline: 1.0773x; 1.0590x over previous
//
#include <hip/hip_runtime.h>
#include <math.h>

#define NN 48
#define CC 512
#define KK 64
#define PP 1600
#define EPSF 1e-12f

typedef short short8 __attribute__((ext_vector_type(8)));
typedef float f32x4 __attribute__((ext_vector_type(4)));

static __device__ __forceinline__ unsigned short f2bf(float f) {
    unsigned u = __float_as_uint(f);
    u += 0x7fffu + ((u >> 16) & 1u);   // round-to-nearest-even
    return (unsigned short)(u >> 16);
}
static __device__ __forceinline__ unsigned pack2(float a, float b) {
    return (unsigned)f2bf(a) | ((unsigned)f2bf(b) << 16);
}

// ---------------------------------------------------------------------------
// Kernel 1: fused norm + attn + logits MFMA-GEMM + softmax.
// grid (25, N), block 256 (4 waves), 64 p per block, c swept in 8 chunks.
// ABLATION this round: xbf writeback REMOVED -> k1 writes only wg (9.8 MB)
// + wsum. If k1 was write-stream-bound, dur drops ~30%+; if unchanged, the
// read path's ~1.6 TB/s effective ceiling is the next target.
// ---------------------------------------------------------------------------
__global__ __launch_bounds__(256, 4) void kn_logits(
    const float* __restrict__ x, const float* __restrict__ conv_w,
    const float* __restrict__ attn_w, const float* __restrict__ attn_b,
    unsigned short* __restrict__ wg, float* __restrict__ wsum)
{
    __shared__ unsigned short xt[64][76];   // [c_local][p] bf16, 152B rows
    __shared__ unsigned short cwb[64][72];  // [k][c_local] bf16, 144B rows
    __shared__ float attn_l[CC];
    __shared__ float red[16][64];
    __shared__ float invn_l[64];
    __shared__ float hmp_l[64];
    __shared__ float wsum_l[KK];

    const int n = blockIdx.y, p0 = blockIdx.x * 64, tid = threadIdx.x;
    const int q = tid & 15, cg = tid >> 4;        // x staging: p-quad, c-row-group
    const int wave = tid >> 6, lane = tid & 63;
    const int lq = lane >> 4, lm = lane & 15;     // MFMA lane decomposition
    const int kr = tid >> 2, cq = tid & 3;        // conv_w staging map

    for (int i = tid; i < CC; i += 256) attn_l[i] = attn_w[i];
    if (tid < KK) wsum_l[tid] = 0.f;

    f32x4 acc[4];
#pragma unroll
    for (int mt = 0; mt < 4; ++mt) acc[mt] = (f32x4){0.f, 0.f, 0.f, 0.f};
    float ss[4] = {0.f, 0.f, 0.f, 0.f};
    float ad[4] = {0.f, 0.f, 0.f, 0.f};

    const float* xb = x + (size_t)n * CC * PP;
    const float* wp0 = conv_w + (size_t)kr * CC + cq * 16;
    const float* xp0 = xb + (size_t)(cg * 4) * PP + p0 + 4 * q;

    // prologue: issue chunk-0 loads
    float4 wv[4], xv[4];
#pragma unroll
    for (int j = 0; j < 4; ++j) wv[j] = *(const float4*)(wp0 + 4 * j);
#pragma unroll
    for (int j = 0; j < 4; ++j) xv[j] = *(const float4*)(xp0 + (size_t)j * PP);

    __syncthreads();   // attn_l / wsum_l ready

#pragma unroll 1
    for (int cs = 0; cs < 8; ++cs) {
        float4 wn[4], xn_[4];
        if (cs < 7) {
            const float* wp = wp0 + (cs + 1) * 64;
            const float* xp = xp0 + (size_t)(cs + 1) * 64 * PP;
#pragma unroll
            for (int j = 0; j < 4; ++j) wn[j] = *(const float4*)(wp + 4 * j);
#pragma unroll
            for (int j = 0; j < 4; ++j) xn_[j] = *(const float4*)(xp + (size_t)j * PP);
        }
        // process conv_w tile (loaded last iteration) -> bf16 LDS
#pragma unroll
        for (int j = 0; j < 4; ++j) {
            uint2 u = {pack2(wv[j].x, wv[j].y), pack2(wv[j].z, wv[j].w)};
            *(uint2*)&cwb[kr][cq * 16 + 4 * j] = u;
        }
        // process x tile: stats + bf16 LDS (NO global writeback)
        const int cbase = cs * 64 + cg * 4;
#pragma unroll
        for (int j = 0; j < 4; ++j) {
            float4 v = xv[j];
            const float aw = attn_l[cbase + j];
            ss[0] += v.x * v.x; ss[1] += v.y * v.y;
            ss[2] += v.z * v.z; ss[3] += v.w * v.w;
            ad[0] += fmaxf(v.x, 0.f) * aw; ad[1] += fmaxf(v.y, 0.f) * aw;
            ad[2] += fmaxf(v.z, 0.f) * aw; ad[3] += fmaxf(v.w, 0.f) * aw;
            uint2 u = {pack2(v.x, v.y), pack2(v.z, v.w)};
            *(uint2*)&xt[cg * 4 + j][4 * q] = u;
        }
        __syncthreads();
#pragma unroll
        for (int ks = 0; ks < 2; ++ks) {
            short8 af[4];
#pragma unroll
            for (int mt = 0; mt < 4; ++mt)
                af[mt] = *(const short8*)&cwb[mt * 16 + lm][ks * 32 + lq * 8];
            const int pl = wave * 16 + lm;
            const int cb = ks * 32 + lq * 8;
            short8 bv;
#pragma unroll
            for (int j = 0; j < 8; ++j) bv[j] = (short)xt[cb + j][pl];
#pragma unroll
            for (int mt = 0; mt < 4; ++mt)
                acc[mt] = __builtin_amdgcn_mfma_f32_16x16x32_bf16(
                    af[mt], bv, acc[mt], 0, 0, 0);
        }
        __syncthreads();
        if (cs < 7) {
#pragma unroll
            for (int j = 0; j < 4; ++j) { wv[j] = wn[j]; xv[j] = xn_[j]; }
        }
    }

    // block reductions: invnorm and hmp per p (fp32)
#pragma unroll
    for (int j = 0; j < 4; ++j) red[cg][4 * q + j] = ss[j];
    __syncthreads();
    if (tid < 64) {
        float S = 0.f;
#pragma unroll
        for (int l = 0; l < 16; ++l) S += red[l][tid];
        invn_l[tid] = 1.f / fmaxf(sqrtf(S), EPSF);
    }
    __syncthreads();
#pragma unroll
    for (int j = 0; j < 4; ++j) red[cg][4 * q + j] = ad[j];
    __syncthreads();
    if (tid < 64) {
        float A = 0.f;
#pragma unroll
        for (int l = 0; l < 16; ++l) A += red[l][tid];
        hmp_l[tid] = fmaxf(A + attn_b[0], 0.f);
    }
    __syncthreads();

    // softmax over k=64 per p, entirely in registers (C-layout + shfl_xor)
    const int pl = wave * 16 + lm;
    const float inv = invn_l[pl];
    const float hp = hmp_l[pl];
    float mx = -1e30f;
#pragma unroll
    for (int mt = 0; mt < 4; ++mt)
#pragma unroll
        for (int r = 0; r < 4; ++r) {
            const float l = acc[mt][r] * inv;
            acc[mt][r] = l;
            mx = fmaxf(mx, l);
        }
    mx = fmaxf(mx, __shfl_xor(mx, 16));
    mx = fmaxf(mx, __shfl_xor(mx, 32));
    float s = 0.f;
#pragma unroll
    for (int mt = 0; mt < 4; ++mt)
#pragma unroll
        for (int r = 0; r < 4; ++r) {
            const float e = __expf(acc[mt][r] - mx);
            acc[mt][r] = e;
            s += e;
        }
    s += __shfl_xor(s, 16);
    s += __shfl_xor(s, 32);
    const float sden = hp / s;

    unsigned short* wrb = wg + (size_t)n * KK * PP + p0;
#pragma unroll
    for (int mt = 0; mt < 4; ++mt)
#pragma unroll
        for (int r = 0; r < 4; ++r) {
            const int k = mt * 16 + lq * 4 + r;
            const float w0 = acc[mt][r] * sden;
            float wk = w0;
#pragma unroll
            for (int o = 1; o < 16; o <<= 1) wk += __shfl_xor(wk, o);
            if (lm == 0) atomicAdd(&wsum_l[k], wk);
            wrb[(size_t)k * PP + pl] = f2bf(w0 * inv);
        }
    __syncthreads();
    if (tid < KK) atomicAdd(&wsum[n * KK + tid], wsum_l[tid]);
}

// ---------------------------------------------------------------------------
// Kernel 2: term1[k,c] = sum_p w'[k,p] * x[c,p] via MFMA (contraction over p).
// grid (8 c-chunks, N, 4 p-chunks) = 1536 blocks (6/CU). x is re-read as
// fp32 (L3-resident after k1 -- 157 MB < 256 MB L3) and converted to bf16
// inline with the same rounding as before. 1-deep register prefetch.
// ---------------------------------------------------------------------------
__global__ __launch_bounds__(256) void kn_term1(
    const float* __restrict__ xf, const unsigned short* __restrict__ wgq,
    float* __restrict__ term1p)
{
    __shared__ unsigned short wt[64][40];    // [k][32p] bf16, rows 80B
    __shared__ unsigned short xt2[64][40];   // [c_local][32p] bf16
    const int c0 = blockIdx.x * 64, n = blockIdx.y, ph = blockIdx.z;
    const int tid = threadIdx.x;
    const int wave = tid >> 6, lane = tid & 63, lq = lane >> 4, lm = lane & 15;
    const int koff = (wave >> 1) * 32, coff = (wave & 1) * 32;
    const int s_begin = (50 * ph) >> 2, s_end = (50 * (ph + 1)) >> 2;
    const int rA = tid >> 2, cq = tid & 3;   // staging map (same for A and B)

    f32x4 acc[2][2];
#pragma unroll
    for (int mt = 0; mt < 2; ++mt)
#pragma unroll
        for (int nt = 0; nt < 2; ++nt) acc[mt][nt] = (f32x4){0.f, 0.f, 0.f, 0.f};

    const unsigned short* wb = wgq + (size_t)n * KK * PP + (size_t)rA * PP + cq * 8;
    const float* xfb = xf + ((size_t)n * CC + c0 + rA) * PP + cq * 8;

    auto ldB = [&](int p) -> uint4 {
        const float* sp = xfb + p;
        float4 a = *(const float4*)sp, b = *(const float4*)(sp + 4);
        return make_uint4(pack2(a.x, a.y), pack2(a.z, a.w),
                          pack2(b.x, b.y), pack2(b.z, b.w));
    };

    uint4 pa = *(const uint4*)(wb + s_begin * 32);
    uint4 pb = ldB(s_begin * 32);

    for (int ps = s_begin; ps < s_end; ++ps) {
        uint4 na, nb;
        if (ps + 1 < s_end) {                 // prefetch next tile (overlaps MFMA)
            na = *(const uint4*)(wb + (ps + 1) * 32);
            nb = ldB((ps + 1) * 32);
        }
        *(uint4*)&wt[rA][cq * 8] = pa;
        *(uint4*)&xt2[rA][cq * 8] = pb;
        __syncthreads();
        short8 af[2], bv[2];
#pragma unroll
        for (int mt = 0; mt < 2; ++mt)
            af[mt] = *(const short8*)&wt[koff + mt * 16 + lm][lq * 8];
#pragma unroll
        for (int nt = 0; nt < 2; ++nt)
            bv[nt] = *(const short8*)&xt2[coff + nt * 16 + lm][lq * 8];
#pragma unroll
        for (int mt = 0; mt < 2; ++mt)
#pragma unroll
            for (int nt = 0; nt < 2; ++nt)
                acc[mt][nt] = __builtin_amdgcn_mfma_f32_16x16x32_bf16(
                    af[mt], bv[nt], acc[mt][nt], 0, 0, 0);
        __syncthreads();
        pa = na; pb = nb;
    }

    float* ob = term1p + ((size_t)ph * NN + n) * KK * CC + c0 + coff;
#pragma unroll
    for (int mt = 0; mt < 2; ++mt)
#pragma unroll
        for (int r = 0; r < 4; ++r) {
            const int k = koff + mt * 16 + lq * 4 + r;
#pragma unroll
            for (int nt = 0; nt < 2; ++nt)
                ob[(size_t)k * CC + nt * 16 + lm] = acc[mt][nt][r];
        }
}

// ---------------------------------------------------------------------------
// Kernel 3: vlad = sum(term1 partials) - wsum*centroids; intra L2-normalize;
// FUSED global normalize: after intra-norm every (n,k) row has sumsq = 1
// (+- few ulp), so the global norm is sqrt(K) = 8 exactly to ~1e-7 rel.
// Fold *0.125 into the store; kn_scale and nsum are deleted.
// grid (K, N), block 128.
// ---------------------------------------------------------------------------
__global__ __launch_bounds__(128) void kn_vlad(
    const float* __restrict__ term1p, const float* __restrict__ wsum,
    const float* __restrict__ cent, float* __restrict__ out)
{
    const int k = blockIdx.x, n = blockIdx.y, tid = threadIdx.x;
    const size_t base = ((size_t)n * KK + k) * CC;
    const size_t NKC = (size_t)NN * KK * CC;
    const float ws = wsum[n * KK + k];
    const int c = tid * 4;

    float4 ce = *(const float4*)(cent + (size_t)k * CC + c);
    float4 v = {-ws * ce.x, -ws * ce.y, -ws * ce.z, -ws * ce.w};
#pragma unroll
    for (int h = 0; h < 4; ++h) {
        float4 a = *(const float4*)(term1p + h * NKC + base + c);
        v.x += a.x; v.y += a.y; v.z += a.z; v.w += a.w;
    }

    float s = v.x * v.x + v.y * v.y + v.z * v.z + v.w * v.w;
#pragma unroll
    for (int o = 32; o >= 1; o >>= 1) s += __shfl_down(s, o, 64);

    __shared__ float rb[2];
    __shared__ float sinv;
    if ((tid & 63) == 0) rb[tid >> 6] = s;
    __syncthreads();
    if (tid == 0) {
        const float S = rb[0] + rb[1];
        sinv = 0.125f / fmaxf(sqrtf(S), EPSF);   // intra-norm * global 1/sqrt(K)
    }
    __syncthreads();
    const float inv = sinv;
    float4 o4 = {v.x * inv, v.y * inv, v.z * inv, v.w * inv};
    *(float4*)(out + base + c) = o4;
}

extern "C" void kernel_launch(void* const* d_in, const int* in_sizes, int n_in,
                              void* d_out, int out_size, void* d_ws, size_t ws_size,
                              hipStream_t stream)
{
    (void)in_sizes; (void)n_in; (void)out_size; (void)ws_size;
    const float* x      = (const float*)d_in[0];
    const float* conv_w = (const float*)d_in[1];
    const float* attn_w = (const float*)d_in[2];
    const float* attn_b = (const float*)d_in[3];
    const float* cent   = (const float*)d_in[4];
    float* out = (float*)d_out;

    // ws layout: term1p[4][N][K][C] f32 | wsum f32 | wg bf16
    char* w = (char*)d_ws;
    float* term1p = (float*)w;            w += (size_t)4 * NN * KK * CC * 4;
    float* wsum   = (float*)w;            w += (size_t)NN * KK * 4;
    unsigned short* wg = (unsigned short*)w;

    hipMemsetAsync(wsum, 0, NN * KK * sizeof(float), stream);

    kn_logits<<<dim3(25, NN), 256, 0, stream>>>(x, conv_w, attn_w, attn_b,
                                                wg, wsum);
    kn_term1<<<dim3(8, NN, 4), 256, 0, stream>>>(x, wg, term1p);
    kn_vlad <<<dim3(KK, NN), 128, 0, stream>>>(term1p, wsum, cent, out);
}

// Round 6
// 279.147 us; speedup vs baseline: 1.1610x; 1.0777x over previous
//
#include <hip/hip_runtime.h>
#include <math.h>

#define NN 48
#define CC 512
#define KK 64
#define PP 1600
#define PH 5          // p-partials (blocks per n)
#define PBLK 320      // p per block
#define SL 32         // p per slice
#define NSL 10        // slices per block
#define EPSF 1e-12f

typedef short short8 __attribute__((ext_vector_type(8)));
typedef float f32x4 __attribute__((ext_vector_type(4)));

static __device__ __forceinline__ unsigned short f2bf(float f) {
    unsigned u = __float_as_uint(f);
    u += 0x7fffu + ((u >> 16) & 1u);   // round-to-nearest-even
    return (unsigned short)(u >> 16);
}
static __device__ __forceinline__ unsigned pack2(float a, float b) {
    return (unsigned)f2bf(a) | ((unsigned)f2bf(b) << 16);
}

// ---------------------------------------------------------------------------
// Kernel 0: pre-convert conv_w fp32 -> bf16 (64 KB, L2-resident; read as
// MFMA A-fragments directly from global by kn_fused).
// ---------------------------------------------------------------------------
__global__ __launch_bounds__(512) void kn_prep(
    const float* __restrict__ conv_w, unsigned short* __restrict__ cwb_g)
{
    const int idx = blockIdx.x * 512 + threadIdx.x;
    cwb_g[idx] = f2bf(conv_w[idx]);
}

// ---------------------------------------------------------------------------
// Kernel 1 (FUSED): norm-stats + attn + logits-MFMA + softmax + term1-MFMA.
// grid (PH, N) = 240 blocks -> ALL resident (<=256 CUs), one round: per-block
// latency == kernel latency, stalls no longer multiply by rounds.
// Block = 512 thr (8 waves). Owns 320 p; 10 slices of 32 p:
//   stage x[512c x 32p] fp32->LDS bf16 (+ stats) -> logits (K=512c, A-frags
//   from L2 bf16 conv) -> cross-wave softmax(k=64) -> w' bf16 -> term1 MFMA
//   (K=32p) accumulating [64k x 512c] across slices in AGPRs.
// x is read EXACTLY ONCE from global; w never round-trips through HBM.
// ---------------------------------------------------------------------------
__global__ __launch_bounds__(512, 2) void kn_fused(
    const float* __restrict__ x, const unsigned short* __restrict__ cwb_g,
    const float* __restrict__ attn_w, const float* __restrict__ attn_b,
    float* __restrict__ wsum, float* __restrict__ term1p)
{
    __shared__ unsigned short xall[512][32];  // [c][p] bf16, 32 KB
    __shared__ unsigned short wlds[64][32];   // [k][p] bf16 w' = sm*hmp*inv
    __shared__ float red_ss[64][32];          // stats partials [group][p]
    __shared__ float red_ad[64][32];
    __shared__ float smx[32][4], ssm[32][4];  // cross-wave softmax [p][kt]
    __shared__ float invn_l[32], hmp_l[32];
    __shared__ float wsum_l[KK];
    __shared__ float attn_l[CC];

    const int ph = blockIdx.x, n = blockIdx.y, tid = threadIdx.x;
    const int wv = tid >> 6, lane = tid & 63;
    const int lq = lane >> 4, lm = lane & 15;
    // pass-A (logits) wave map: 4 kt x 2 p-halves
    const int kt = wv >> 1, ph2 = wv & 1;
    const int pl = ph2 * 16 + lm;             // p within slice (0..31)
    // pass-B (term1) wave map: 2 k-halves x 4 c-quarters
    const int kb = wv >> 2, cb = wv & 3;
    // stage map: row 0..63 within c-chunk, p-quad 0..7
    const int sr = tid >> 3, sq = tid & 7;

    attn_l[tid] = attn_w[tid];
    if (tid >= 512 - KK) wsum_l[tid - (512 - KK)] = 0.f;
    const float ab = attn_b[0];

    f32x4 acc2[2][8];
#pragma unroll
    for (int mt = 0; mt < 2; ++mt)
#pragma unroll
        for (int nt = 0; nt < 8; ++nt) acc2[mt][nt] = (f32x4){0.f, 0.f, 0.f, 0.f};

    const float* xb = x + (size_t)n * CC * PP + ph * PBLK;
    // A-fragments for logits: this lane's conv row, cached across all slices
    const unsigned short* afb = cwb_g + (size_t)(kt * 16 + lm) * CC;
    short8 af_all[16];
#pragma unroll
    for (int t = 0; t < 16; ++t)
        af_all[t] = *(const short8*)(afb + t * 32 + lq * 8);

    __syncthreads();   // attn_l / wsum_l ready

    for (int sl = 0; sl < NSL; ++sl) {
        const int ps = sl * SL;
        // ---- stage x slice: 8 chunks of 64 c; batch loads then consume ----
        float ss[4] = {0.f, 0.f, 0.f, 0.f};
        float ad[4] = {0.f, 0.f, 0.f, 0.f};
        float4 xv[8];
#pragma unroll
        for (int cs = 0; cs < 8; ++cs)
            xv[cs] = *(const float4*)(xb + (size_t)(cs * 64 + sr) * PP + ps + sq * 4);
#pragma unroll
        for (int cs = 0; cs < 8; ++cs) {
            const float4 v = xv[cs];
            const float aw = attn_l[cs * 64 + sr];
            ss[0] += v.x * v.x; ss[1] += v.y * v.y;
            ss[2] += v.z * v.z; ss[3] += v.w * v.w;
            ad[0] += fmaxf(v.x, 0.f) * aw; ad[1] += fmaxf(v.y, 0.f) * aw;
            ad[2] += fmaxf(v.z, 0.f) * aw; ad[3] += fmaxf(v.w, 0.f) * aw;
            uint2 u = {pack2(v.x, v.y), pack2(v.z, v.w)};
            *(uint2*)&xall[cs * 64 + sr][sq * 4] = u;
        }
#pragma unroll
        for (int j = 0; j < 4; ++j) {
            red_ss[sr][sq * 4 + j] = ss[j];
            red_ad[sr][sq * 4 + j] = ad[j];
        }
        __syncthreads();   // xall + red ready

        // ---- per-p reductions: invnorm + heatmap ----
        if (tid < 32) {
            float S = 0.f;
#pragma unroll 8
            for (int g = 0; g < 64; ++g) S += red_ss[g][tid];
            invn_l[tid] = 1.f / fmaxf(sqrtf(S), EPSF);
        } else if (tid < 64) {
            const int p = tid - 32;
            float A = 0.f;
#pragma unroll 8
            for (int g = 0; g < 64; ++g) A += red_ad[g][p];
            hmp_l[p] = fmaxf(A + ab, 0.f);
        }
        __syncthreads();

        // ---- logits MFMA: out [16k x 16p] per wave, K = 512 c ----
        f32x4 a1 = (f32x4){0.f, 0.f, 0.f, 0.f};
#pragma unroll
        for (int t = 0; t < 16; ++t) {
            const int cb8 = t * 32 + lq * 8;
            short8 bv;
#pragma unroll
            for (int j = 0; j < 8; ++j) bv[j] = (short)xall[cb8 + j][pl];
            a1 = __builtin_amdgcn_mfma_f32_16x16x32_bf16(af_all[t], bv, a1, 0, 0, 0);
        }

        // ---- softmax over k=64 (in-wave over 16 k, cross-wave over 4 kt) ----
        const float inv = invn_l[pl], hp = hmp_l[pl];
        float l0[4];
        float mxw = -1e30f;
#pragma unroll
        for (int r = 0; r < 4; ++r) {
            l0[r] = a1[r] * inv;
            mxw = fmaxf(mxw, l0[r]);
        }
        mxw = fmaxf(mxw, __shfl_xor(mxw, 16));
        mxw = fmaxf(mxw, __shfl_xor(mxw, 32));
        if (lq == 0) smx[pl][kt] = mxw;
        __syncthreads();
        const float mx = fmaxf(fmaxf(smx[pl][0], smx[pl][1]),
                               fmaxf(smx[pl][2], smx[pl][3]));
        float e[4];
        float sw = 0.f;
#pragma unroll
        for (int r = 0; r < 4; ++r) {
            e[r] = __expf(l0[r] - mx);
            sw += e[r];
        }
        sw += __shfl_xor(sw, 16);
        sw += __shfl_xor(sw, 32);
        if (lq == 0) ssm[pl][kt] = sw;
        __syncthreads();
        const float s = ssm[pl][0] + ssm[pl][1] + ssm[pl][2] + ssm[pl][3];
        const float sden = hp / s;

        // ---- w0 = sm*hmp: wsum partials + w' = w0*inv -> wlds bf16 ----
#pragma unroll
        for (int r = 0; r < 4; ++r) {
            const float w0 = e[r] * sden;
            float wk = w0;
#pragma unroll
            for (int o = 1; o < 16; o <<= 1) wk += __shfl_xor(wk, o);
            if (lm == 0) atomicAdd(&wsum_l[kt * 16 + lq * 4 + r], wk);
            wlds[kt * 16 + lq * 4 + r][pl] = f2bf(w0 * inv);
        }
        __syncthreads();   // wlds ready

        // ---- term1 MFMA: out [32k x 128c] per wave, K = 32 p ----
        short8 af2[2], bv2[8];
#pragma unroll
        for (int mt = 0; mt < 2; ++mt)
            af2[mt] = *(const short8*)&wlds[kb * 32 + mt * 16 + lm][lq * 8];
#pragma unroll
        for (int nt = 0; nt < 8; ++nt)
            bv2[nt] = *(const short8*)&xall[cb * 128 + nt * 16 + lm][lq * 8];
#pragma unroll
        for (int mt = 0; mt < 2; ++mt)
#pragma unroll
            for (int nt = 0; nt < 8; ++nt)
                acc2[mt][nt] = __builtin_amdgcn_mfma_f32_16x16x32_bf16(
                    af2[mt], bv2[nt], acc2[mt][nt], 0, 0, 0);
        __syncthreads();   // done with xall/wlds before next slice overwrite
    }

    // ---- epilogue: term1 partial [64k x 512c] -> term1p[ph][n], wsum ----
    float* ob = term1p + ((size_t)ph * NN + n) * KK * CC;
#pragma unroll
    for (int mt = 0; mt < 2; ++mt)
#pragma unroll
        for (int r = 0; r < 4; ++r) {
            const int k = kb * 32 + mt * 16 + lq * 4 + r;
#pragma unroll
            for (int nt = 0; nt < 8; ++nt)
                ob[(size_t)k * CC + cb * 128 + nt * 16 + lm] = acc2[mt][nt][r];
        }
    if (tid < KK) atomicAdd(&wsum[n * KK + tid], wsum_l[tid]);
}

// ---------------------------------------------------------------------------
// Kernel 2: vlad = sum(term1 partials) - wsum*centroids; intra L2-normalize;
// fused global normalize (after intra-norm per-n sumsq == K -> factor 0.125).
// grid (K, N), block 128.
// ---------------------------------------------------------------------------
__global__ __launch_bounds__(128) void kn_vlad(
    const float* __restrict__ term1p, const float* __restrict__ wsum,
    const float* __restrict__ cent, float* __restrict__ out)
{
    const int k = blockIdx.x, n = blockIdx.y, tid = threadIdx.x;
    const size_t base = ((size_t)n * KK + k) * CC;
    const size_t NKC = (size_t)NN * KK * CC;
    const float ws = wsum[n * KK + k];
    const int c = tid * 4;

    float4 ce = *(const float4*)(cent + (size_t)k * CC + c);
    float4 v = {-ws * ce.x, -ws * ce.y, -ws * ce.z, -ws * ce.w};
#pragma unroll
    for (int h = 0; h < PH; ++h) {
        float4 a = *(const float4*)(term1p + h * NKC + base + c);
        v.x += a.x; v.y += a.y; v.z += a.z; v.w += a.w;
    }

    float s = v.x * v.x + v.y * v.y + v.z * v.z + v.w * v.w;
#pragma unroll
    for (int o = 32; o >= 1; o >>= 1) s += __shfl_down(s, o, 64);

    __shared__ float rb[2];
    __shared__ float sinv;
    if ((tid & 63) == 0) rb[tid >> 6] = s;
    __syncthreads();
    if (tid == 0) {
        const float S = rb[0] + rb[1];
        sinv = 0.125f / fmaxf(sqrtf(S), EPSF);   // intra-norm * global 1/sqrt(K)
    }
    __syncthreads();
    const float inv = sinv;
    float4 o4 = {v.x * inv, v.y * inv, v.z * inv, v.w * inv};
    *(float4*)(out + base + c) = o4;
}

extern "C" void kernel_launch(void* const* d_in, const int* in_sizes, int n_in,
                              void* d_out, int out_size, void* d_ws, size_t ws_size,
                              hipStream_t stream)
{
    (void)in_sizes; (void)n_in; (void)out_size; (void)ws_size;
    const float* x      = (const float*)d_in[0];
    const float* conv_w = (const float*)d_in[1];
    const float* attn_w = (const float*)d_in[2];
    const float* attn_b = (const float*)d_in[3];
    const float* cent   = (const float*)d_in[4];
    float* out = (float*)d_out;

    // ws layout: term1p[PH][N][K][C] f32 | wsum f32 (pad) | cwb_g bf16
    char* w = (char*)d_ws;
    float* term1p = (float*)w;            w += (size_t)PH * NN * KK * CC * 4;
    float* wsum   = (float*)w;            w += ((size_t)NN * KK * 4 + 255) & ~255ULL;
    unsigned short* cwb_g = (unsigned short*)w;

    hipMemsetAsync(wsum, 0, NN * KK * sizeof(float), stream);

    kn_prep <<<dim3(KK * CC / 512), 512, 0, stream>>>(conv_w, cwb_g);
    kn_fused<<<dim3(PH, NN), 512, 0, stream>>>(x, cwb_g, attn_w, attn_b,
                                               wsum, term1p);
    kn_vlad <<<dim3(KK, NN), 128, 0, stream>>>(term1p, wsum, cent, out);
}